// Round 11
// baseline (131.907 us; speedup 1.0000x reference)
//
#include <hip/hip_runtime.h>
#include <math.h>

// Problem constants
#define BB 128
#define ND 32
#define NIJ 16384
#define EPS2 0.25f
#define EPS4 0.0625f

// Tiling: 256 blocks x 64 ij, full batch per block
// 512 thr = 64 b-pairs x 8 q-lanes; thread: 2 b x 8 ij
#define TIJ 64
#define NBLK (NIJ / TIJ)        // 256
#define NTHR 512
#define QN 8
#define IJT (TIJ / QN)          // 8 ij per thread
#define ROWF 132                // coef row: cA32|cB32|K32|KV32|pad4

// LDS layout (floats): coef[64][132] = 8448, then CC(64), LAM(64).
// Epilogue stage [128][36] = 4608 aliases the coef region.
#define CC_OFF  8448
#define LAM_OFF 8512
#define LDS_FL  8576            // 34.3 KB
#define STG_ROW 36

// part layout per block (packed): num[128][32] @0, den[128] @4096
#define PART_STRIDE 4224
#define DEN_OFF_P 4096

__global__ __launch_bounds__(NTHR, 2) void gmm_fused(
    const float* __restrict__ Xg,
    const float* __restrict__ tptr,
    const float* __restrict__ Mu0, const float* __restrict__ Mu1,
    const float* __restrict__ S0,  const float* __restrict__ S1,
    const float* __restrict__ Lam,
    float* __restrict__ part)
{
    __shared__ __align__(16) float lds[LDS_FL];

    const int tid  = threadIdx.x;
    const int blk  = blockIdx.x;
    const int ij0g = blk * TIJ;
    const float t   = tptr[0];
    const float omt = 1.0f - t;

    // ---- X for this thread's b-pair: direct global -> registers ----
    const int g  = tid >> 3;      // 0..63 b-pair
    const int q  = tid & 7;       // ij-lane
    const int b0 = 2 * g;
    const int b1 = 2 * g + 1;
    float x0[ND], x1[ND];
#pragma unroll
    for (int c = 0; c < 8; ++c) {
        const float4 v0 = ((const float4*)(Xg + b0 * ND))[c];
        const float4 v1 = ((const float4*)(Xg + b1 * ND))[c];
        x0[4*c+0] = v0.x; x0[4*c+1] = v0.y; x0[4*c+2] = v0.z; x0[4*c+3] = v0.w;
        x1[4*c+0] = v1.x; x1[4*c+1] = v1.y; x1[4*c+2] = v1.z; x1[4*c+3] = v1.w;
    }

    // ---- Phase 1: per-(ij, n) coefficients into LDS (each exactly once) ----
    // 64 ij * 32 n = 2048 pairs over 512 threads -> 4 each
#pragma unroll
    for (int k = 0; k < (TIJ * ND) / NTHR; ++k) {
        const int idx = tid + k * NTHR;
        const int ijl = idx >> 5;          // 0..63
        const int n   = idx & 31;
        const int ij  = ij0g + ijl;
        const int i   = ij >> 7;
        const int j   = ij & 127;
        const float s0  = S0[i * ND + n];
        const float s1  = S1[j * ND + n];
        const float mu0 = Mu0[i * ND + n];
        const float mu1 = Mu1[j * ND + n];
        const float Ds  = sqrtf(4.0f * s0 * s1 + EPS4);
        const float Cs  = 0.5f * (Ds - EPS2);
        const float Sigma = omt * omt * s0 + t * t * s1
                          + 2.0f * t * omt * Cs + EPS2 * t * omt;
        const float St  = (t * s1 + omt * Cs) - (omt * s0 + t * Cs) - EPS2 * t;
        const float Mut = omt * mu0 + t * mu1;
        const float v   = mu1 - mu0;
        const float invS = 1.0f / Sigma;
        const float Kf  = St * invS;
        const float cA  = -0.5f * invS;
        const float cB  = Mut * invS;
        lds[ijl * ROWF + n]      = cA;
        lds[ijl * ROWF + 32 + n] = cB;
        lds[ijl * ROWF + 64 + n] = Kf;
        lds[ijl * ROWF + 96 + n] = v - Kf * Mut;
        float cc = cA * Mut * Mut - 0.5f * __logf(Sigma);
        cc += __shfl_xor(cc, 1);
        cc += __shfl_xor(cc, 2);
        cc += __shfl_xor(cc, 4);
        cc += __shfl_xor(cc, 8);
        cc += __shfl_xor(cc, 16);
        if (n == 0) lds[CC_OFF + ijl] = cc;
    }
    if (tid < TIJ) lds[LAM_OFF + tid] = Lam[ij0g + tid];

    float num0[ND], num1[ND];
#pragma unroll
    for (int n = 0; n < ND; ++n) { num0[n] = 0.0f; num1[n] = 0.0f; }
    float den0 = 0.0f, den1 = 0.0f;

    __syncthreads();

    // ---- Phase 2: thread does 2 b x 8 ij; 8 distinct rows/wave (banks
    //      offset 4*ijl mod 32 -> conflict-free), coef read ONCE per 2 b ----
#pragma unroll
    for (int it = 0; it < IJT; ++it) {
        const int ijl = q + it * QN;
        const float* __restrict__ row = &lds[ijl * ROWF];
        const float cc0 = lds[CC_OFF + ijl];
        float lw0a = cc0, lw0b = 0.0f, lw1a = cc0, lw1b = 0.0f;
#pragma unroll
        for (int nc = 0; nc < 8; ++nc) {
            const float4 a  = *(const float4*)&row[nc * 4];
            const float4 bq = *(const float4*)&row[32 + nc * 4];
            lw0a = fmaf(fmaf(a.x, x0[nc*4+0], bq.x), x0[nc*4+0], lw0a);
            lw1a = fmaf(fmaf(a.x, x1[nc*4+0], bq.x), x1[nc*4+0], lw1a);
            lw0b = fmaf(fmaf(a.y, x0[nc*4+1], bq.y), x0[nc*4+1], lw0b);
            lw1b = fmaf(fmaf(a.y, x1[nc*4+1], bq.y), x1[nc*4+1], lw1b);
            lw0a = fmaf(fmaf(a.z, x0[nc*4+2], bq.z), x0[nc*4+2], lw0a);
            lw1a = fmaf(fmaf(a.z, x1[nc*4+2], bq.z), x1[nc*4+2], lw1a);
            lw0b = fmaf(fmaf(a.w, x0[nc*4+3], bq.w), x0[nc*4+3], lw0b);
            lw1b = fmaf(fmaf(a.w, x1[nc*4+3], bq.w), x1[nc*4+3], lw1b);
        }
        const float lam = lds[LAM_OFF + ijl];
        float lw0 = lw0a + lw0b;
        float lw1 = lw1a + lw1b;
        lw0 = fminf(fmaxf(lw0, -50.0f), 50.0f);
        lw1 = fminf(fmaxf(lw1, -50.0f), 50.0f);
        const float w0 = __expf(lw0) * lam;
        const float w1 = __expf(lw1) * lam;
        den0 += w0;
        den1 += w1;
#pragma unroll
        for (int nc = 0; nc < 8; ++nc) {
            const float4 kk = *(const float4*)&row[64 + nc * 4];
            const float4 kv = *(const float4*)&row[96 + nc * 4];
            num0[nc*4+0] = fmaf(w0, fmaf(kk.x, x0[nc*4+0], kv.x), num0[nc*4+0]);
            num1[nc*4+0] = fmaf(w1, fmaf(kk.x, x1[nc*4+0], kv.x), num1[nc*4+0]);
            num0[nc*4+1] = fmaf(w0, fmaf(kk.y, x0[nc*4+1], kv.y), num0[nc*4+1]);
            num1[nc*4+1] = fmaf(w1, fmaf(kk.y, x1[nc*4+1], kv.y), num1[nc*4+1]);
            num0[nc*4+2] = fmaf(w0, fmaf(kk.z, x0[nc*4+2], kv.z), num0[nc*4+2]);
            num1[nc*4+2] = fmaf(w1, fmaf(kk.z, x1[nc*4+2], kv.z), num1[nc*4+2]);
            num0[nc*4+3] = fmaf(w0, fmaf(kk.w, x0[nc*4+3], kv.w), num0[nc*4+3]);
            num1[nc*4+3] = fmaf(w1, fmaf(kk.w, x1[nc*4+3], kv.w), num1[nc*4+3]);
        }
    }

    // ---- Reduce across the 8 q-lanes (lane bits 0-2) ----
#pragma unroll
    for (int m = 1; m <= 4; m <<= 1) {
        den0 += __shfl_xor(den0, m);
        den1 += __shfl_xor(den1, m);
#pragma unroll
        for (int n = 0; n < ND; ++n) {
            num0[n] += __shfl_xor(num0[n], m);
            num1[n] += __shfl_xor(num1[n], m);
        }
    }

    __syncthreads();   // phase-2 LDS reads done before stage overwrites coef

    // ---- Stage into LDS [128][36] rows (2-way banks) ----
    if (q == 0) {
#pragma unroll
        for (int c = 0; c < 8; ++c) {
            *(float4*)&lds[b0 * STG_ROW + 4 * c] =
                make_float4(num0[4*c], num0[4*c+1], num0[4*c+2], num0[4*c+3]);
            *(float4*)&lds[b1 * STG_ROW + 4 * c] =
                make_float4(num1[4*c], num1[4*c+1], num1[4*c+2], num1[4*c+3]);
        }
        lds[b0 * STG_ROW + 32] = den0;
        lds[b1 * STG_ROW + 32] = den1;
    }

    __syncthreads();

    // ---- Coalesced packed block store: 4224 floats, full 128B lines ----
    float* __restrict__ dstg = part + (size_t)blk * PART_STRIDE;
#pragma unroll
    for (int k = 0; k < 3; ++k) {
        const int kk = tid + k * NTHR;     // 1056 float4s used
        if (kk < PART_STRIDE / 4) {
            const int p = 4 * kk;
            float4 val;
            if (p < DEN_OFF_P) {
                val = *(const float4*)&lds[(p >> 5) * STG_ROW + (p & 31)];
            } else {
                const int d = p - DEN_OFF_P;
                val = make_float4(lds[(d + 0) * STG_ROW + 32],
                                  lds[(d + 1) * STG_ROW + 32],
                                  lds[(d + 2) * STG_ROW + 32],
                                  lds[(d + 3) * STG_ROW + 32]);
            }
            *(float4*)(dstg + p) = val;
        }
    }
}

// 256 blocks = (b, n-half). Thread (sg, n16): sums 16 slices; LDS combine.
__global__ __launch_bounds__(256) void gmm_reduce(
    const float* __restrict__ part,
    float* __restrict__ out)
{
    const int blk = blockIdx.x;            // 0..255
    const int b   = blk >> 1;
    const int nh  = blk & 1;
    const int tid = threadIdx.x;
    const int n16 = tid & 15;
    const int sg  = tid >> 4;              // 0..15 slice-groups
    const int n   = nh * 16 + n16;

    float num = 0.0f, den = 0.0f;
#pragma unroll
    for (int g = 0; g < 16; ++g) {
        const int s = sg + g * 16;         // slice 0..255
        const size_t base = (size_t)s * PART_STRIDE;
        num += part[base + b * 32 + n];
        den += part[base + DEN_OFF_P + b]; // same addr across n16 -> broadcast
    }

    __shared__ float red[16][18];
    red[sg][n16] = num;
    if (n16 == 0) red[sg][16] = den;
    __syncthreads();

    if (tid < 16) {
        float ns = 0.0f, ds = 0.0f;
#pragma unroll
        for (int k = 0; k < 16; ++k) {
            ns += red[k][tid];
            ds += red[k][16];
        }
        out[b * 32 + nh * 16 + tid] = ns / ds;
    }
}

extern "C" void kernel_launch(void* const* d_in, const int* in_sizes, int n_in,
                              void* d_out, int out_size, void* d_ws, size_t ws_size,
                              hipStream_t stream)
{
    const float* X   = (const float*)d_in[0];
    const float* t   = (const float*)d_in[1];
    const float* Mu0 = (const float*)d_in[2];
    const float* Mu1 = (const float*)d_in[3];
    const float* S0  = (const float*)d_in[4];
    const float* S1  = (const float*)d_in[5];
    const float* Lam = (const float*)d_in[6];
    float* out  = (float*)d_out;
    float* part = (float*)d_ws;             // NBLK * PART_STRIDE floats (4.3 MB)

    gmm_fused<<<NBLK, NTHR, 0, stream>>>(X, t, Mu0, Mu1, S0, S1, Lam, part);
    gmm_reduce<<<2 * BB, 256, 0, stream>>>(part, out);
}

// Round 12
// 84.259 us; speedup vs baseline: 1.5655x; 1.5655x over previous
//
#include <hip/hip_runtime.h>
#include <math.h>

// Problem constants
#define BB 128
#define ND 32
#define NIJ 16384
#define EPS2 0.25f
#define EPS4 0.0625f

// Tiling: 256 blocks x 64 ij, full batch per block
// 512 thr = 64 b-pairs x 8 q-lanes; thread: 2 b x 8 ij
#define TIJ 64
#define NBLK (NIJ / TIJ)        // 256
#define NTHR 512
#define QN 8
#define IJT (TIJ / QN)          // 8 ij per thread
#define ROWF 132                // coef row: cA32|cB32|K32|KV32|pad4

// LDS layout (floats): coef[64][132] = 8448, then CC(64), LAM(64).
// Epilogue stage [128][36] = 4608 aliases the coef region.
#define CC_OFF  8448
#define LAM_OFF 8512
#define LDS_FL  8576            // 34.3 KB
#define STG_ROW 36

// part layout per block (packed): num[128][32] @0, den[128] @4096
#define PART_STRIDE 4224
#define DEN_OFF_P 4096

__global__ __launch_bounds__(NTHR, 2) void gmm_fused(
    const float* __restrict__ Xg,
    const float* __restrict__ tptr,
    const float* __restrict__ Mu0, const float* __restrict__ Mu1,
    const float* __restrict__ S0,  const float* __restrict__ S1,
    const float* __restrict__ Lam,
    float* __restrict__ part)
{
    __shared__ __align__(16) float lds[LDS_FL];

    const int tid  = threadIdx.x;
    const int blk  = blockIdx.x;
    const int ij0g = blk * TIJ;
    const float t   = tptr[0];
    const float omt = 1.0f - t;

    // ---- X for this thread's b-pair: direct global -> registers ----
    const int g  = tid >> 3;      // 0..63 b-pair
    const int q  = tid & 7;       // ij-lane
    const int b0 = 2 * g;
    const int b1 = 2 * g + 1;
    float x0[ND], x1[ND];
#pragma unroll
    for (int c = 0; c < 8; ++c) {
        const float4 v0 = ((const float4*)(Xg + b0 * ND))[c];
        const float4 v1 = ((const float4*)(Xg + b1 * ND))[c];
        x0[4*c+0] = v0.x; x0[4*c+1] = v0.y; x0[4*c+2] = v0.z; x0[4*c+3] = v0.w;
        x1[4*c+0] = v1.x; x1[4*c+1] = v1.y; x1[4*c+2] = v1.z; x1[4*c+3] = v1.w;
    }

    // ---- Phase 1: per-(ij, n) coefficients into LDS (each exactly once) ----
    // 64 ij * 32 n = 2048 pairs over 512 threads -> 4 each
#pragma unroll
    for (int k = 0; k < (TIJ * ND) / NTHR; ++k) {
        const int idx = tid + k * NTHR;
        const int ijl = idx >> 5;          // 0..63
        const int n   = idx & 31;
        const int ij  = ij0g + ijl;
        const int i   = ij >> 7;
        const int j   = ij & 127;
        const float s0  = S0[i * ND + n];
        const float s1  = S1[j * ND + n];
        const float mu0 = Mu0[i * ND + n];
        const float mu1 = Mu1[j * ND + n];
        const float Ds  = sqrtf(4.0f * s0 * s1 + EPS4);
        const float Cs  = 0.5f * (Ds - EPS2);
        const float Sigma = omt * omt * s0 + t * t * s1
                          + 2.0f * t * omt * Cs + EPS2 * t * omt;
        const float St  = (t * s1 + omt * Cs) - (omt * s0 + t * Cs) - EPS2 * t;
        const float Mut = omt * mu0 + t * mu1;
        const float v   = mu1 - mu0;
        const float invS = 1.0f / Sigma;
        const float Kf  = St * invS;
        const float cA  = -0.5f * invS;
        const float cB  = Mut * invS;
        lds[ijl * ROWF + n]      = cA;
        lds[ijl * ROWF + 32 + n] = cB;
        lds[ijl * ROWF + 64 + n] = Kf;
        lds[ijl * ROWF + 96 + n] = v - Kf * Mut;
        float cc = cA * Mut * Mut - 0.5f * __logf(Sigma);
        cc += __shfl_xor(cc, 1);
        cc += __shfl_xor(cc, 2);
        cc += __shfl_xor(cc, 4);
        cc += __shfl_xor(cc, 8);
        cc += __shfl_xor(cc, 16);
        if (n == 0) lds[CC_OFF + ijl] = cc;
    }
    if (tid < TIJ) lds[LAM_OFF + tid] = Lam[ij0g + tid];

    float num0[ND], num1[ND];
#pragma unroll
    for (int n = 0; n < ND; ++n) { num0[n] = 0.0f; num1[n] = 0.0f; }
    float den0 = 0.0f, den1 = 0.0f;

    __syncthreads();

    // ---- Phase 2: thread does 2 b x 8 ij; 8 distinct rows/wave (banks
    //      offset 4*ijl mod 32 -> conflict-free), coef read ONCE per 2 b.
    //      NOTE: unroll(1) is load-bearing — full unroll spills (R11: 266 MB
    //      scratch traffic, 64 us). R2/R3 rolled loop = VGPR 84, no spill. ----
#pragma unroll 1
    for (int it = 0; it < IJT; ++it) {
        const int ijl = q + it * QN;
        const float* __restrict__ row = &lds[ijl * ROWF];
        const float cc0 = lds[CC_OFF + ijl];
        float lw0a = cc0, lw0b = 0.0f, lw1a = cc0, lw1b = 0.0f;
#pragma unroll
        for (int nc = 0; nc < 8; ++nc) {
            const float4 a  = *(const float4*)&row[nc * 4];
            const float4 bq = *(const float4*)&row[32 + nc * 4];
            lw0a = fmaf(fmaf(a.x, x0[nc*4+0], bq.x), x0[nc*4+0], lw0a);
            lw1a = fmaf(fmaf(a.x, x1[nc*4+0], bq.x), x1[nc*4+0], lw1a);
            lw0b = fmaf(fmaf(a.y, x0[nc*4+1], bq.y), x0[nc*4+1], lw0b);
            lw1b = fmaf(fmaf(a.y, x1[nc*4+1], bq.y), x1[nc*4+1], lw1b);
            lw0a = fmaf(fmaf(a.z, x0[nc*4+2], bq.z), x0[nc*4+2], lw0a);
            lw1a = fmaf(fmaf(a.z, x1[nc*4+2], bq.z), x1[nc*4+2], lw1a);
            lw0b = fmaf(fmaf(a.w, x0[nc*4+3], bq.w), x0[nc*4+3], lw0b);
            lw1b = fmaf(fmaf(a.w, x1[nc*4+3], bq.w), x1[nc*4+3], lw1b);
        }
        const float lam = lds[LAM_OFF + ijl];
        float lw0 = lw0a + lw0b;
        float lw1 = lw1a + lw1b;
        lw0 = fminf(fmaxf(lw0, -50.0f), 50.0f);
        lw1 = fminf(fmaxf(lw1, -50.0f), 50.0f);
        const float w0 = __expf(lw0) * lam;
        const float w1 = __expf(lw1) * lam;
        den0 += w0;
        den1 += w1;
#pragma unroll
        for (int nc = 0; nc < 8; ++nc) {
            const float4 kk = *(const float4*)&row[64 + nc * 4];
            const float4 kv = *(const float4*)&row[96 + nc * 4];
            num0[nc*4+0] = fmaf(w0, fmaf(kk.x, x0[nc*4+0], kv.x), num0[nc*4+0]);
            num1[nc*4+0] = fmaf(w1, fmaf(kk.x, x1[nc*4+0], kv.x), num1[nc*4+0]);
            num0[nc*4+1] = fmaf(w0, fmaf(kk.y, x0[nc*4+1], kv.y), num0[nc*4+1]);
            num1[nc*4+1] = fmaf(w1, fmaf(kk.y, x1[nc*4+1], kv.y), num1[nc*4+1]);
            num0[nc*4+2] = fmaf(w0, fmaf(kk.z, x0[nc*4+2], kv.z), num0[nc*4+2]);
            num1[nc*4+2] = fmaf(w1, fmaf(kk.z, x1[nc*4+2], kv.z), num1[nc*4+2]);
            num0[nc*4+3] = fmaf(w0, fmaf(kk.w, x0[nc*4+3], kv.w), num0[nc*4+3]);
            num1[nc*4+3] = fmaf(w1, fmaf(kk.w, x1[nc*4+3], kv.w), num1[nc*4+3]);
        }
    }

    // ---- Reduce across the 8 q-lanes (lane bits 0-2) ----
#pragma unroll
    for (int m = 1; m <= 4; m <<= 1) {
        den0 += __shfl_xor(den0, m);
        den1 += __shfl_xor(den1, m);
#pragma unroll
        for (int n = 0; n < ND; ++n) {
            num0[n] += __shfl_xor(num0[n], m);
            num1[n] += __shfl_xor(num1[n], m);
        }
    }

    __syncthreads();   // phase-2 LDS reads done before stage overwrites coef

    // ---- Stage into LDS [128][36] rows (2-way banks) ----
    if (q == 0) {
#pragma unroll
        for (int c = 0; c < 8; ++c) {
            *(float4*)&lds[b0 * STG_ROW + 4 * c] =
                make_float4(num0[4*c], num0[4*c+1], num0[4*c+2], num0[4*c+3]);
            *(float4*)&lds[b1 * STG_ROW + 4 * c] =
                make_float4(num1[4*c], num1[4*c+1], num1[4*c+2], num1[4*c+3]);
        }
        lds[b0 * STG_ROW + 32] = den0;
        lds[b1 * STG_ROW + 32] = den1;
    }

    __syncthreads();

    // ---- Coalesced packed block store: 4224 floats, full 128B lines ----
    float* __restrict__ dstg = part + (size_t)blk * PART_STRIDE;
#pragma unroll
    for (int k = 0; k < 3; ++k) {
        const int kk = tid + k * NTHR;     // 1056 float4s used
        if (kk < PART_STRIDE / 4) {
            const int p = 4 * kk;
            float4 val;
            if (p < DEN_OFF_P) {
                val = *(const float4*)&lds[(p >> 5) * STG_ROW + (p & 31)];
            } else {
                const int d = p - DEN_OFF_P;
                val = make_float4(lds[(d + 0) * STG_ROW + 32],
                                  lds[(d + 1) * STG_ROW + 32],
                                  lds[(d + 2) * STG_ROW + 32],
                                  lds[(d + 3) * STG_ROW + 32]);
            }
            *(float4*)(dstg + p) = val;
        }
    }
}

// 256 blocks = (b, n-half). Thread (sg, n16): sums 16 slices; LDS combine.
__global__ __launch_bounds__(256) void gmm_reduce(
    const float* __restrict__ part,
    float* __restrict__ out)
{
    const int blk = blockIdx.x;            // 0..255
    const int b   = blk >> 1;
    const int nh  = blk & 1;
    const int tid = threadIdx.x;
    const int n16 = tid & 15;
    const int sg  = tid >> 4;              // 0..15 slice-groups
    const int n   = nh * 16 + n16;

    float num = 0.0f, den = 0.0f;
#pragma unroll
    for (int g = 0; g < 16; ++g) {
        const int s = sg + g * 16;         // slice 0..255
        const size_t base = (size_t)s * PART_STRIDE;
        num += part[base + b * 32 + n];
        den += part[base + DEN_OFF_P + b]; // same addr across n16 -> broadcast
    }

    __shared__ float red[16][18];
    red[sg][n16] = num;
    if (n16 == 0) red[sg][16] = den;
    __syncthreads();

    if (tid < 16) {
        float ns = 0.0f, ds = 0.0f;
#pragma unroll
        for (int k = 0; k < 16; ++k) {
            ns += red[k][tid];
            ds += red[k][16];
        }
        out[b * 32 + nh * 16 + tid] = ns / ds;
    }
}

extern "C" void kernel_launch(void* const* d_in, const int* in_sizes, int n_in,
                              void* d_out, int out_size, void* d_ws, size_t ws_size,
                              hipStream_t stream)
{
    const float* X   = (const float*)d_in[0];
    const float* t   = (const float*)d_in[1];
    const float* Mu0 = (const float*)d_in[2];
    const float* Mu1 = (const float*)d_in[3];
    const float* S0  = (const float*)d_in[4];
    const float* S1  = (const float*)d_in[5];
    const float* Lam = (const float*)d_in[6];
    float* out  = (float*)d_out;
    float* part = (float*)d_ws;             // NBLK * PART_STRIDE floats (4.3 MB)

    gmm_fused<<<NBLK, NTHR, 0, stream>>>(X, t, Mu0, Mu1, S0, S1, Lam, part);
    gmm_reduce<<<2 * BB, 256, 0, stream>>>(part, out);
}